// Round 13
// baseline (200.489 us; speedup 1.0000x reference)
//
#include <hip/hip_runtime.h>

typedef __attribute__((ext_vector_type(8))) short short8;
typedef __attribute__((ext_vector_type(4))) float f32x4;
typedef __attribute__((ext_vector_type(4))) unsigned short u16x4;

#define NN 2048
#define KG2 448
#define NK1 15
#define NG1 8
#define NF1 64
#define SLICE (2048L * 2048L)
#define XSL (64L * 2048L)
#define HSL (512L * 2048L)

static __device__ __forceinline__ unsigned short f2bf(float v) {
    union { float f; unsigned int u; } a; a.f = v;
    unsigned int u = a.u;
    u += 0x7fffu + ((u >> 16) & 1u);   // round-to-nearest-even
    return (unsigned short)(u >> 16);
}
static __device__ __forceinline__ float bf2f(unsigned short s) {
    union { float f; unsigned int u; } a; a.u = ((unsigned int)s) << 16;
    return a.f;
}
static __device__ __forceinline__ float sigmoidf_(float v) {
    return 1.f / (1.f + __expf(-v));
}
template <int N> static __device__ __forceinline__ void waitvm() {
    asm volatile("s_waitcnt vmcnt(%0)" ::"n"(N) : "memory");
}
template <int LPT> static __device__ __forceinline__ void waitrem(int rem) {
    if (rem >= 7) waitvm<7 * LPT>();
    else if (rem == 6) waitvm<6 * LPT>();
    else if (rem == 5) waitvm<5 * LPT>();
    else if (rem == 4) waitvm<4 * LPT>();
    else if (rem == 3) waitvm<3 * LPT>();
    else if (rem == 2) waitvm<2 * LPT>();
    else if (rem == 1) waitvm<1 * LPT>();
    else waitvm<0>();
}

// ---------------------------------------------------------------------------
// GEMM core (256 threads): C[BM,BN] += A[BM,K](bf16 rm) @ Bt[BN,K](bf16 rm)^T
// Both operands via global_load_lds (linear tiles).
// PIPE>1: counted-vmcnt deep prefetch (latency-bound small grids).
// ---------------------------------------------------------------------------
template <int BM, int BN, int PIPE>
static __device__ __forceinline__ void gemm_core(
    const unsigned short* __restrict__ Ap, int lda,
    const unsigned short* __restrict__ Bp, int ldb, int K,
    unsigned short* Alds, unsigned short* Blds,
    f32x4 (&acc)[BM / 32][BN / 32], int tid) {
    constexpr int MI = BM / 32, NI = BN / 32;
    constexpr int ACH = BM / 64, BCH = BN / 64;
    constexpr int LPT = ACH + BCH;
    const int lane = tid & 63;
    const int wv = tid >> 6;
    const int q = lane >> 4, r = lane & 15;
    const int wm = (wv >> 1) * (BM / 2), wn = (wv & 1) * (BN / 2);

    auto stage = [&](int k0, int buf) {
        unsigned short* Ab = Alds + buf * (BM * 32);
        unsigned short* Bb = Blds + buf * (BN * 32);
#pragma unroll
        for (int c = 0; c < ACH; ++c) {
            const int row = (tid >> 2) + c * 64;
            const unsigned short* gp = Ap + (long)row * lda + k0 + (tid & 3) * 8;
            char* lb = (char*)Ab + c * 4096 + wv * 1024;  // wave-uniform base
            __builtin_amdgcn_global_load_lds(
                (const __attribute__((address_space(1))) void*)gp,
                (__attribute__((address_space(3))) void*)lb, 16, 0, 0);
        }
#pragma unroll
        for (int c = 0; c < BCH; ++c) {
            const int row = (tid >> 2) + c * 64;
            const unsigned short* gp = Bp + (long)row * ldb + k0 + (tid & 3) * 8;
            char* lb = (char*)Bb + c * 4096 + wv * 1024;
            __builtin_amdgcn_global_load_lds(
                (const __attribute__((address_space(1))) void*)gp,
                (__attribute__((address_space(3))) void*)lb, 16, 0, 0);
        }
    };
    auto compute = [&](int buf) {
        const unsigned short* Ab = Alds + buf * (BM * 32);
        const unsigned short* Bb = Blds + buf * (BN * 32);
        short8 af[MI], bfv[NI];
#pragma unroll
        for (int i = 0; i < MI; ++i)
            af[i] = *(const short8*)&Ab[(wm + i * 16 + r) * 32 + q * 8];
#pragma unroll
        for (int j = 0; j < NI; ++j)
            bfv[j] = *(const short8*)&Bb[(wn + j * 16 + r) * 32 + q * 8];
#pragma unroll
        for (int i = 0; i < MI; ++i)
#pragma unroll
            for (int j = 0; j < NI; ++j)
                acc[i][j] = __builtin_amdgcn_mfma_f32_16x16x32_bf16(
                    af[i], bfv[j], acc[i][j], 0, 0, 0);
    };

    const int NT = K >> 5;
#pragma unroll
    for (int p = 0; p < PIPE - 1; ++p)
        if (p < NT) stage(p * 32, p);
    for (int t = 0; t < NT; ++t) {
        if (t + PIPE - 1 < NT)
            stage((t + PIPE - 1) * 32, (t + PIPE - 1) % PIPE);
        int rem = NT - 1 - t;
        if (rem > PIPE - 1) rem = PIPE - 1;
        waitrem<LPT>(rem);
        __builtin_amdgcn_s_barrier();
        compute(t % PIPE);
        __builtin_amdgcn_s_barrier();
    }
}

// epilogue: plain bf16 row-major store. C/D layout: col=lane&15, row=q*4+e
template <int BM, int BN>
static __device__ __forceinline__ void epi_bf16(
    f32x4 (&acc)[BM / 32][BN / 32], unsigned short* dst, int ld, int tid) {
    const int lane = tid & 63, wv = tid >> 6, q = lane >> 4, r = lane & 15;
    const int wm = (wv >> 1) * (BM / 2), wn = (wv & 1) * (BN / 2);
#pragma unroll
    for (int i = 0; i < BM / 32; ++i)
#pragma unroll
        for (int j = 0; j < BN / 32; ++j)
#pragma unroll
            for (int e = 0; e < 4; ++e)
                dst[(long)(wm + i * 16 + q * 4 + e) * ld + wn + j * 16 + r] =
                    f2bf(acc[i][j][e]);
}

// epilogue: z2t scatter. rows = b*64+g -> z2t[(b*2048+col)*448 + kidx*64 + g]
template <int BM, int BN>
static __device__ __forceinline__ void epi_z2t(
    f32x4 (&acc)[BM / 32][BN / 32], unsigned short* z2t,
    int m0, int n0, int kidx, int tid) {
    const int lane = tid & 63, wv = tid >> 6, q = lane >> 4, r = lane & 15;
    const int wm = (wv >> 1) * (BM / 2), wn = (wv & 1) * (BN / 2);
#pragma unroll
    for (int i = 0; i < BM / 32; ++i)
#pragma unroll
        for (int j = 0; j < BN / 32; ++j) {
            const int row0 = m0 + wm + i * 16 + q * 4;
            const int bb = row0 >> 6, gg = row0 & 63;
            const int col = n0 + wn + j * 16 + r;
            u16x4 pk;
            pk[0] = f2bf(acc[i][j][0]); pk[1] = f2bf(acc[i][j][1]);
            pk[2] = f2bf(acc[i][j][2]); pk[3] = f2bf(acc[i][j][3]);
            *(u16x4*)&z2t[((long)bb * NN + col) * KG2 + kidx * 64 + gg] = pk;
        }
}

// ---------------------------------------------------------------------------
// prep: St transpose+cvt (z<2); x cvt (z==2)
// ---------------------------------------------------------------------------
__global__ __launch_bounds__(256) void prep_k(const float* __restrict__ S,
                                              const float* __restrict__ x,
                                              unsigned short* __restrict__ St,
                                              unsigned short* __restrict__ xbf) {
    if (blockIdx.z < 2) {
        __shared__ float t[32][33];
        const int e = blockIdx.z;
        const int n0 = blockIdx.x * 32, k0 = blockIdx.y * 32;
        const int tx = threadIdx.x & 31, ty = threadIdx.x >> 5;
        const float* src = S + (long)e * SLICE;
        unsigned short* dst = St + (long)e * SLICE;
#pragma unroll
        for (int i = 0; i < 4; ++i)
            t[ty + i * 8][tx] = src[(long)(k0 + ty + i * 8) * NN + n0 + tx];
        __syncthreads();
#pragma unroll
        for (int i = 0; i < 4; ++i)
            dst[(long)(n0 + ty + i * 8) * NN + k0 + tx] = f2bf(t[tx][ty + i * 8]);
    } else {
        const long i = (long)(blockIdx.y * 64 + blockIdx.x) * 256 + threadIdx.x;
        if (i < 131072L) xbf[i] = f2bf(x[i]);
    }
}

// ---------------------------------------------------------------------------
// g1_k: out[z] = A_slice @ St[z&1]^T   (M=64, BN=64, K=2048), PIPE=8
// ---------------------------------------------------------------------------
template <int PIPE>
__global__ __launch_bounds__(256) void g1_k(const unsigned short* __restrict__ A,
                                            long a_bstride, int a_shr,
                                            const unsigned short* __restrict__ St,
                                            unsigned short* __restrict__ outp) {
    __shared__ __attribute__((aligned(16))) unsigned short smem[PIPE * 128 * 32];
    const int tid = threadIdx.x;
    const int n0 = blockIdx.x * 64;
    const int z = blockIdx.z;
    const unsigned short* Ap = A + (long)(z >> a_shr) * a_bstride;
    const unsigned short* Bp = St + (long)(z & 1) * SLICE + (long)n0 * NN;

    f32x4 acc[2][2];
#pragma unroll
    for (int i = 0; i < 2; ++i)
#pragma unroll
        for (int j = 0; j < 2; ++j) acc[i][j] = (f32x4){0.f, 0.f, 0.f, 0.f};
    gemm_core<64, 64, PIPE>(Ap, NN, Bp, NN, NN, smem, smem + PIPE * 64 * 32,
                            acc, tid);
    epi_bf16<64, 64>(acc, outp + (long)z * XSL + n0, NN, tid);
}

// ---------------------------------------------------------------------------
// g2_k: slice GEMM (M=512 via by, BN=64, K=2048) -> z2t scatter (+opt chain)
// BN=64 quadruples block count vs R11 (TLP for the latency-bound middle).
// ---------------------------------------------------------------------------
template <int PIPE, bool CHAIN>
__global__ __launch_bounds__(256) void g2_k(const unsigned short* __restrict__ A,
                                            long a_bstride, int a_shr,
                                            const unsigned short* __restrict__ St,
                                            unsigned short* __restrict__ z2t,
                                            int kbase,
                                            unsigned short* __restrict__ chain) {
    __shared__ __attribute__((aligned(16))) unsigned short smem[PIPE * 128 * 32];
    const int tid = threadIdx.x;
    const int n0 = blockIdx.x * 64;
    const int m0 = blockIdx.y * 64;
    const int z = blockIdx.z;
    const unsigned short* Ap = A + (long)(z >> a_shr) * a_bstride + (long)m0 * NN;
    const unsigned short* Bp = St + (long)(z & 1) * SLICE + (long)n0 * NN;

    f32x4 acc[2][2];
#pragma unroll
    for (int i = 0; i < 2; ++i)
#pragma unroll
        for (int j = 0; j < 2; ++j) acc[i][j] = (f32x4){0.f, 0.f, 0.f, 0.f};
    gemm_core<64, 64, PIPE>(Ap, NN, Bp, NN, NN, smem, smem + PIPE * 64 * 32,
                            acc, tid);
    epi_z2t<64, 64>(acc, z2t, m0, n0, kbase + z, tid);
    if (CHAIN)
        epi_bf16<64, 64>(acc, chain + (long)z * HSL + (long)m0 * NN + n0, NN, tid);
}

// ---------------------------------------------------------------------------
// combine1: by<8: h = sigmoid(sum w1*z1 + b1) -> A2 + z2t k=0
//           by>=8: side work (w2 fp32->bf16)
// ---------------------------------------------------------------------------
__global__ __launch_bounds__(256) void combine1_k(const float* __restrict__ x,
                                                  const unsigned short* __restrict__ xSbf,
                                                  const float* __restrict__ w1,
                                                  const float* __restrict__ b1,
                                                  const float* __restrict__ w2,
                                                  unsigned short* __restrict__ A2,
                                                  unsigned short* __restrict__ z2t,
                                                  unsigned short* __restrict__ w2bf) {
    const int tid = threadIdx.x;
    if (blockIdx.y >= 8) {
        // side: w2 cvt (229376 float4s)
        const int sb = (blockIdx.y - 8) * 16 + blockIdx.x;  // 0..127
        for (long i4 = (long)sb * 256 + tid; i4 < 229376L; i4 += 32768L) {
            const float4 v = *(const float4*)&w2[i4 * 4];
            u16x4 pk;
            pk[0] = f2bf(v.x); pk[1] = f2bf(v.y);
            pk[2] = f2bf(v.z); pk[3] = f2bf(v.w);
            *(u16x4*)&w2bf[i4 * 4] = pk;
        }
        return;
    }
    __shared__ float w1s[NF1 * NK1 * NG1];
    for (int i = tid; i < NF1 * NK1 * NG1; i += 256) w1s[i] = w1[i];
    __syncthreads();

    const int b = blockIdx.y;
    const int n = blockIdx.x * 128 + (tid & 127);
    const int fh = tid >> 7;

    float accv[32];
#pragma unroll
    for (int f = 0; f < 32; ++f) accv[f] = 0.f;

    for (int k = 0; k < NK1; ++k) {
        float vv[NG1];
#pragma unroll
        for (int g = 0; g < NG1; ++g) {
            if (k == 0) vv[g] = x[(long)(b * 8 + g) * NN + n];
            else vv[g] = bf2f(xSbf[(long)(k - 1) * XSL + (long)(b * 8 + g) * NN + n]);
        }
#pragma unroll
        for (int f = 0; f < 32; ++f) {
            const float* wp = &w1s[((fh * 32 + f) * NK1 + k) * NG1];
            float s = 0.f;
#pragma unroll
            for (int g = 0; g < NG1; ++g) s += vv[g] * wp[g];
            accv[f] += s;
        }
    }
    unsigned short hb[32];
#pragma unroll
    for (int f = 0; f < 32; ++f) {
        const int fg = fh * 32 + f;
        const float h = sigmoidf_(accv[f] + b1[fg]);
        hb[f] = f2bf(h);
        A2[(long)(b * 64 + fg) * NN + n] = hb[f];
    }
    const long zb = ((long)(b * NN + n)) * KG2 + fh * 32;
#pragma unroll
    for (int c = 0; c < 4; ++c) {
        short8 v;
#pragma unroll
        for (int jj = 0; jj < 8; ++jj) v[jj] = (short)hb[c * 8 + jj];
        *(short8*)&z2t[zb + c * 8] = v;
    }
}

// ---------------------------------------------------------------------------
// g3_k: partial[np][m][2] = wlin . sigmoid(w2 @ z2 + b2), atomic-free.
// R11-proven form: BM=128, BN=256, 512 thr, BK=64 single-buffer m97,
// XOR-swizzled LDS both sides, batch-aligned XCD swizzle, (512,4) bounds.
// ---------------------------------------------------------------------------
__global__ __launch_bounds__(512, 4) void g3_k(
    const unsigned short* __restrict__ w2bf,
    const unsigned short* __restrict__ z2t,
    const float* __restrict__ b2, const float* __restrict__ wlin,
    float* __restrict__ partial) {
    __shared__ __attribute__((aligned(16))) unsigned short Asm[128 * 64];  // 16 KB
    __shared__ __attribute__((aligned(16))) unsigned short Bsm[256 * 64];  // 32 KB
    __shared__ float ored[128][2];                                         //  1 KB
    const int tid = threadIdx.x;
    const int bid = blockIdx.x;                     // 1024 blocks
    const int xcd = bid & 7, j = bid >> 3;          // j in [0,128)
    const int np = xcd * 8 + (j >> 4);              // n-panel id [0,64)
    const int n0 = np * 256;                        // batch = np>>3 = xcd
    const int m0 = (j & 15) * 128;                  // 16 m-tiles
    const int lane = tid & 63, wv = tid >> 6;       // 8 waves
    const int q = lane >> 4, r = lane & 15;
    const int wm = (wv >> 2) * 64, wn = (wv & 3) * 64;  // 2m x 4n wave grid
    const int qs = (tid & 7) ^ ((tid >> 3) & 7);    // pre-swizzled source quad
    const int rx = r & 7;                           // row&7 for frag reads

    const unsigned short* Ap = w2bf + (long)m0 * KG2;
    const unsigned short* Bp = z2t + (long)n0 * KG2;

    f32x4 acc[4][4];
#pragma unroll
    for (int i = 0; i < 4; ++i)
#pragma unroll
        for (int j2 = 0; j2 < 4; ++j2) acc[i][j2] = (f32x4){0.f, 0.f, 0.f, 0.f};

    for (int t = 0; t < 7; ++t) {   // K = 448 = 7 x 64
        const int k0 = t * 64;
#pragma unroll
        for (int c = 0; c < 2; ++c) {   // A: 128 rows x 64, 2 passes
            const int row = (tid >> 3) + c * 64;
            const unsigned short* gp = Ap + (long)row * KG2 + k0 + qs * 8;
            char* lb = (char*)Asm + c * 8192 + wv * 1024;  // wave-uniform base
            __builtin_amdgcn_global_load_lds(
                (const __attribute__((address_space(1))) void*)gp,
                (__attribute__((address_space(3))) void*)lb, 16, 0, 0);
        }
#pragma unroll
        for (int c = 0; c < 4; ++c) {   // B: 256 rows x 64, 4 passes
            const int row = (tid >> 3) + c * 64;
            const unsigned short* gp = Bp + (long)row * KG2 + k0 + qs * 8;
            char* lb = (char*)Bsm + c * 8192 + wv * 1024;
            __builtin_amdgcn_global_load_lds(
                (const __attribute__((address_space(1))) void*)gp,
                (__attribute__((address_space(3))) void*)lb, 16, 0, 0);
        }
        __syncthreads();
#pragma unroll
        for (int kk = 0; kk < 2; ++kk) {
            short8 af[4], bfv[4];
#pragma unroll
            for (int i = 0; i < 4; ++i)
                af[i] = *(const short8*)&Asm[(wm + i * 16 + r) * 64 +
                                             (((kk * 4 + q) ^ rx) * 8)];
#pragma unroll
            for (int j2 = 0; j2 < 4; ++j2)
                bfv[j2] = *(const short8*)&Bsm[(wn + j2 * 16 + r) * 64 +
                                               (((kk * 4 + q) ^ rx) * 8)];
#pragma unroll
            for (int i = 0; i < 4; ++i)
#pragma unroll
                for (int j2 = 0; j2 < 4; ++j2)
                    acc[i][j2] = __builtin_amdgcn_mfma_f32_16x16x32_bf16(
                        af[i], bfv[j2], acc[i][j2], 0, 0, 0);
        }
        __syncthreads();
    }

    // fused epilogue: sigmoid + dot(wlin) + LDS reduce -> private partial tile
    if (tid < 128) { ored[tid][0] = 0.f; ored[tid][1] = 0.f; }
    __syncthreads();
    float wl0[4], wl1[4];
#pragma unroll
    for (int j2 = 0; j2 < 4; ++j2) {
        const int nn = (n0 + wn + j2 * 16 + r) & (NN - 1);
        wl0[j2] = wlin[nn];
        wl1[j2] = wlin[NN + nn];
    }
#pragma unroll
    for (int i = 0; i < 4; ++i) {
#pragma unroll
        for (int e = 0; e < 4; ++e) {
            const int lrow = wm + i * 16 + q * 4 + e;
            const float bs = b2[m0 + lrow];
            float p0 = 0.f, p1 = 0.f;
#pragma unroll
            for (int j2 = 0; j2 < 4; ++j2) {
                const float s = sigmoidf_(acc[i][j2][e] + bs);
                p0 += s * wl0[j2];
                p1 += s * wl1[j2];
            }
#pragma unroll
            for (int mk = 1; mk < 16; mk <<= 1) {
                p0 += __shfl_xor(p0, mk);
                p1 += __shfl_xor(p1, mk);
            }
            if (r == 0) {
                atomicAdd(&ored[lrow][0], p0);   // LDS atomic (intra-block)
                atomicAdd(&ored[lrow][1], p1);
            }
        }
    }
    __syncthreads();
    // non-atomic private store: partial[(np*2048 + m0+i)*2 + o]
    float* pp = partial + ((long)np * NN + m0) * 2;
    if (tid < 128) {
        pp[tid * 2 + 0] = ored[tid][0];
        pp[tid * 2 + 1] = ored[tid][1];
    }
}

// ---------------------------------------------------------------------------
// finish: out[b*4096 + f*2 + o] = |sigmoid(sum_{s<8} partial[((b*8+s)*2048+f)*2+o]
//                                          + blin[o])|
// ---------------------------------------------------------------------------
__global__ __launch_bounds__(256) void finish_k(const float* __restrict__ partial,
                                                const float* __restrict__ blin,
                                                float* __restrict__ out) {
    const int i = blockIdx.x * 256 + threadIdx.x;   // 32768 outputs
    if (i >= 32768) return;
    const int b = i >> 12;
    const int fo = i & 4095;                        // f*2 + o
    float s = 0.f;
#pragma unroll
    for (int p = 0; p < 8; ++p)
        s += partial[(long)(b * 8 + p) * 4096 + fo];
    out[i] = fabsf(sigmoidf_(s + blin[i & 1]));
}

// ---------------------------------------------------------------------------
extern "C" void kernel_launch(void* const* d_in, const int* in_sizes, int n_in,
                              void* d_out, int out_size, void* d_ws, size_t ws_size,
                              hipStream_t stream) {
    const float* x      = (const float*)d_in[0];
    const float* terms1 = (const float*)d_in[1];  // slices 0,1 are S0,S1
    const float* w1     = (const float*)d_in[3];
    const float* b1     = (const float*)d_in[4];
    const float* w2     = (const float*)d_in[5];
    const float* b2     = (const float*)d_in[6];
    const float* wlin   = (const float*)d_in[7];
    const float* blin   = (const float*)d_in[8];
    float* out = (float*)d_out;

    char* ws = (char*)d_ws;
    unsigned short* xbf   = (unsigned short*)(ws + 0);          //   262144 B
    unsigned short* w2bf  = (unsigned short*)(ws + 262144);     //  1835008 B
    unsigned short* St    = (unsigned short*)(ws + 2097152);    // 16777216 B
    unsigned short* xSbf  = (unsigned short*)(ws + 18874368);   //  3670016 B
    unsigned short* A2    = (unsigned short*)(ws + 22544384);   //  2097152 B
    unsigned short* hS1bf = (unsigned short*)(ws + 24641536);   //  4194304 B
    unsigned short* z2t   = (unsigned short*)(ws + 28835840);   // 14680064 B
    float*          part  = (float*)(ws + 43515904);            //  1048576 B

    // 1) prep: St transpose + x cvt
    prep_k<<<dim3(64, 64, 3), 256, 0, stream>>>(terms1, x, St, xbf);

    // 2) G1 chain (M=64, N=2048, K=2048), PIPE=8 deep prefetch
    g1_k<8><<<dim3(32, 1, 2), 256, 0, stream>>>(xbf, 0L, 30, St, xSbf);
    g1_k<8><<<dim3(32, 1, 4), 256, 0, stream>>>(xSbf, XSL, 1, St, xSbf + 2 * XSL);
    g1_k<8><<<dim3(32, 1, 8), 256, 0, stream>>>(xSbf + 2 * XSL, XSL, 1, St,
                                                xSbf + 6 * XSL);

    // 3) combine1 -> A2 + z2t k=0; side blocks do w2 cvt
    combine1_k<<<dim3(16, 16), 256, 0, stream>>>(x, xSbf, w1, b1, w2, A2, z2t,
                                                 w2bf);

    // 4) G2 chain, BN=64 4x-block grids: hS1 (512 blk) then hS2 (1024 blk)
    g2_k<6, true><<<dim3(32, 8, 2), 256, 0, stream>>>(A2, 0L, 30, St, z2t, 1,
                                                      hS1bf);
    g2_k<6, false><<<dim3(32, 8, 4), 256, 0, stream>>>(hS1bf, HSL, 1, St, z2t, 3,
                                                       nullptr);

    // 5) G3 (R11 single-buffer, atomic-free) + 6) finish reduce
    g3_k<<<1024, 512, 0, stream>>>(w2bf, z2t, b2, wlin, part);
    finish_k<<<128, 256, 0, stream>>>(part, blin, out);
}

// Round 14
// 171.376 us; speedup vs baseline: 1.1699x; 1.1699x over previous
//
#include <hip/hip_runtime.h>

typedef __attribute__((ext_vector_type(8))) short short8;
typedef __attribute__((ext_vector_type(4))) float f32x4;
typedef __attribute__((ext_vector_type(4))) unsigned short u16x4;

#define NN 2048
#define KG2 448
#define NK1 15
#define NG1 8
#define NF1 64
#define SLICE (2048L * 2048L)
#define XSL (64L * 2048L)
#define HSL (512L * 2048L)

static __device__ __forceinline__ unsigned short f2bf(float v) {
    union { float f; unsigned int u; } a; a.f = v;
    unsigned int u = a.u;
    u += 0x7fffu + ((u >> 16) & 1u);   // round-to-nearest-even
    return (unsigned short)(u >> 16);
}
static __device__ __forceinline__ float bf2f(unsigned short s) {
    union { float f; unsigned int u; } a; a.u = ((unsigned int)s) << 16;
    return a.f;
}
static __device__ __forceinline__ float sigmoidf_(float v) {
    return 1.f / (1.f + __expf(-v));
}
template <int N> static __device__ __forceinline__ void waitvm() {
    asm volatile("s_waitcnt vmcnt(%0)" ::"n"(N) : "memory");
}
template <int LPT> static __device__ __forceinline__ void waitrem(int rem) {
    if (rem >= 7) waitvm<7 * LPT>();
    else if (rem == 6) waitvm<6 * LPT>();
    else if (rem == 5) waitvm<5 * LPT>();
    else if (rem == 4) waitvm<4 * LPT>();
    else if (rem == 3) waitvm<3 * LPT>();
    else if (rem == 2) waitvm<2 * LPT>();
    else if (rem == 1) waitvm<1 * LPT>();
    else waitvm<0>();
}

// ---------------------------------------------------------------------------
// gemm_core64 (256 threads): C[BM,BN] += A[BM,K] @ Bt[BN,K]^T, bf16, BK=64.
// XOR-swizzled LDS on BOTH sides (rule #21): thread loads global quad
// qs=(tid&7)^(row&7) into linear LDS slot tid&7; frag read XORs back.
// 2-way bank conflicts (free, m136) instead of BK=32's 8-way.
// Counted-vmcnt PIPE-deep prefetch; 32 K-iters (half the barrier events).
// ---------------------------------------------------------------------------
template <int BM, int BN, int PIPE>
static __device__ __forceinline__ void gemm_core64(
    const unsigned short* __restrict__ Ap, int lda,
    const unsigned short* __restrict__ Bp, int ldb, int K,
    unsigned short* Alds, unsigned short* Blds,
    f32x4 (&acc)[BM / 32][BN / 32], int tid) {
    constexpr int MI = BM / 32, NI = BN / 32;
    constexpr int APASS = BM / 32, BPASS = BN / 32;   // 32 rows per pass
    constexpr int LPT = APASS + BPASS;
    const int lane = tid & 63;
    const int wv = tid >> 6;
    const int q = lane >> 4, r = lane & 15;
    const int wm = (wv >> 1) * (BM / 2), wn = (wv & 1) * (BN / 2);
    const int qs = (tid & 7) ^ ((tid >> 3) & 7);      // pre-swizzled quad
    const int rx = r & 7;

    auto stage = [&](int k0, int buf) {
        unsigned short* Ab = Alds + buf * (BM * 64);
        unsigned short* Bb = Blds + buf * (BN * 64);
#pragma unroll
        for (int c = 0; c < APASS; ++c) {
            const int row = (tid >> 3) + c * 32;
            const unsigned short* gp = Ap + (long)row * lda + k0 + qs * 8;
            char* lb = (char*)Ab + c * 4096 + wv * 1024;   // wave-uniform
            __builtin_amdgcn_global_load_lds(
                (const __attribute__((address_space(1))) void*)gp,
                (__attribute__((address_space(3))) void*)lb, 16, 0, 0);
        }
#pragma unroll
        for (int c = 0; c < BPASS; ++c) {
            const int row = (tid >> 3) + c * 32;
            const unsigned short* gp = Bp + (long)row * ldb + k0 + qs * 8;
            char* lb = (char*)Bb + c * 4096 + wv * 1024;
            __builtin_amdgcn_global_load_lds(
                (const __attribute__((address_space(1))) void*)gp,
                (__attribute__((address_space(3))) void*)lb, 16, 0, 0);
        }
    };
    auto compute = [&](int buf) {
        const unsigned short* Ab = Alds + buf * (BM * 64);
        const unsigned short* Bb = Blds + buf * (BN * 64);
#pragma unroll
        for (int kk = 0; kk < 2; ++kk) {
            short8 af[MI], bfv[NI];
#pragma unroll
            for (int i = 0; i < MI; ++i)
                af[i] = *(const short8*)&Ab[(wm + i * 16 + r) * 64 +
                                            (((kk * 4 + q) ^ rx) * 8)];
#pragma unroll
            for (int j = 0; j < NI; ++j)
                bfv[j] = *(const short8*)&Bb[(wn + j * 16 + r) * 64 +
                                             (((kk * 4 + q) ^ rx) * 8)];
#pragma unroll
            for (int i = 0; i < MI; ++i)
#pragma unroll
                for (int j = 0; j < NI; ++j)
                    acc[i][j] = __builtin_amdgcn_mfma_f32_16x16x32_bf16(
                        af[i], bfv[j], acc[i][j], 0, 0, 0);
        }
    };

    const int NT = K >> 6;   // BK = 64
#pragma unroll
    for (int p = 0; p < PIPE - 1; ++p)
        if (p < NT) stage(p * 64, p);
    for (int t = 0; t < NT; ++t) {
        if (t + PIPE - 1 < NT)
            stage((t + PIPE - 1) * 64, (t + PIPE - 1) % PIPE);
        int rem = NT - 1 - t;
        if (rem > PIPE - 1) rem = PIPE - 1;
        waitrem<LPT>(rem);
        __builtin_amdgcn_s_barrier();
        compute(t % PIPE);
        __builtin_amdgcn_s_barrier();
    }
}

// epilogue: plain bf16 row-major store. C/D layout: col=lane&15, row=q*4+e
template <int BM, int BN>
static __device__ __forceinline__ void epi_bf16(
    f32x4 (&acc)[BM / 32][BN / 32], unsigned short* dst, int ld, int tid) {
    const int lane = tid & 63, wv = tid >> 6, q = lane >> 4, r = lane & 15;
    const int wm = (wv >> 1) * (BM / 2), wn = (wv & 1) * (BN / 2);
#pragma unroll
    for (int i = 0; i < BM / 32; ++i)
#pragma unroll
        for (int j = 0; j < BN / 32; ++j)
#pragma unroll
            for (int e = 0; e < 4; ++e)
                dst[(long)(wm + i * 16 + q * 4 + e) * ld + wn + j * 16 + r] =
                    f2bf(acc[i][j][e]);
}

// epilogue: z2t scatter. rows = b*64+g -> z2t[(b*2048+col)*448 + kidx*64 + g]
template <int BM, int BN>
static __device__ __forceinline__ void epi_z2t(
    f32x4 (&acc)[BM / 32][BN / 32], unsigned short* z2t,
    int m0, int n0, int kidx, int tid) {
    const int lane = tid & 63, wv = tid >> 6, q = lane >> 4, r = lane & 15;
    const int wm = (wv >> 1) * (BM / 2), wn = (wv & 1) * (BN / 2);
#pragma unroll
    for (int i = 0; i < BM / 32; ++i)
#pragma unroll
        for (int j = 0; j < BN / 32; ++j) {
            const int row0 = m0 + wm + i * 16 + q * 4;
            const int bb = row0 >> 6, gg = row0 & 63;
            const int col = n0 + wn + j * 16 + r;
            u16x4 pk;
            pk[0] = f2bf(acc[i][j][0]); pk[1] = f2bf(acc[i][j][1]);
            pk[2] = f2bf(acc[i][j][2]); pk[3] = f2bf(acc[i][j][3]);
            *(u16x4*)&z2t[((long)bb * NN + col) * KG2 + kidx * 64 + gg] = pk;
        }
}

// ---------------------------------------------------------------------------
// prep: St transpose+cvt (z<2); x cvt (z==2)
// ---------------------------------------------------------------------------
__global__ __launch_bounds__(256) void prep_k(const float* __restrict__ S,
                                              const float* __restrict__ x,
                                              unsigned short* __restrict__ St,
                                              unsigned short* __restrict__ xbf) {
    if (blockIdx.z < 2) {
        __shared__ float t[32][33];
        const int e = blockIdx.z;
        const int n0 = blockIdx.x * 32, k0 = blockIdx.y * 32;
        const int tx = threadIdx.x & 31, ty = threadIdx.x >> 5;
        const float* src = S + (long)e * SLICE;
        unsigned short* dst = St + (long)e * SLICE;
#pragma unroll
        for (int i = 0; i < 4; ++i)
            t[ty + i * 8][tx] = src[(long)(k0 + ty + i * 8) * NN + n0 + tx];
        __syncthreads();
#pragma unroll
        for (int i = 0; i < 4; ++i)
            dst[(long)(n0 + ty + i * 8) * NN + k0 + tx] = f2bf(t[tx][ty + i * 8]);
    } else {
        const long i = (long)(blockIdx.y * 64 + blockIdx.x) * 256 + threadIdx.x;
        if (i < 131072L) xbf[i] = f2bf(x[i]);
    }
}

// ---------------------------------------------------------------------------
// g1_k: out[z] = A_slice @ St[z&1]^T   (M=64, BN=64, K=2048), BK=64, PIPE=6
// ---------------------------------------------------------------------------
template <int PIPE>
__global__ __launch_bounds__(256) void g1_k(const unsigned short* __restrict__ A,
                                            long a_bstride, int a_shr,
                                            const unsigned short* __restrict__ St,
                                            unsigned short* __restrict__ outp) {
    __shared__ __attribute__((aligned(16))) unsigned short smem[PIPE * 128 * 64];
    const int tid = threadIdx.x;
    const int n0 = blockIdx.x * 64;
    const int z = blockIdx.z;
    const unsigned short* Ap = A + (long)(z >> a_shr) * a_bstride;
    const unsigned short* Bp = St + (long)(z & 1) * SLICE + (long)n0 * NN;

    f32x4 acc[2][2];
#pragma unroll
    for (int i = 0; i < 2; ++i)
#pragma unroll
        for (int j = 0; j < 2; ++j) acc[i][j] = (f32x4){0.f, 0.f, 0.f, 0.f};
    gemm_core64<64, 64, PIPE>(Ap, NN, Bp, NN, NN, smem, smem + PIPE * 64 * 64,
                              acc, tid);
    epi_bf16<64, 64>(acc, outp + (long)z * XSL + n0, NN, tid);
}

// ---------------------------------------------------------------------------
// g2_k: slice GEMM (M=512 via by, BN=128, K=2048) -> z2t scatter (+opt chain)
// BK=64, PIPE=3 (72 KB LDS -> 2 blocks/CU)
// ---------------------------------------------------------------------------
template <int PIPE, bool CHAIN>
__global__ __launch_bounds__(256) void g2_k(const unsigned short* __restrict__ A,
                                            long a_bstride, int a_shr,
                                            const unsigned short* __restrict__ St,
                                            unsigned short* __restrict__ z2t,
                                            int kbase,
                                            unsigned short* __restrict__ chain) {
    __shared__ __attribute__((aligned(16))) unsigned short smem[PIPE * 192 * 64];
    const int tid = threadIdx.x;
    const int n0 = blockIdx.x * 128;
    const int m0 = blockIdx.y * 64;
    const int z = blockIdx.z;
    const unsigned short* Ap = A + (long)(z >> a_shr) * a_bstride + (long)m0 * NN;
    const unsigned short* Bp = St + (long)(z & 1) * SLICE + (long)n0 * NN;

    f32x4 acc[2][4];
#pragma unroll
    for (int i = 0; i < 2; ++i)
#pragma unroll
        for (int j = 0; j < 4; ++j) acc[i][j] = (f32x4){0.f, 0.f, 0.f, 0.f};
    gemm_core64<64, 128, PIPE>(Ap, NN, Bp, NN, NN, smem, smem + PIPE * 64 * 64,
                               acc, tid);
    epi_z2t<64, 128>(acc, z2t, m0, n0, kbase + z, tid);
    if (CHAIN)
        epi_bf16<64, 128>(acc, chain + (long)z * HSL + (long)m0 * NN + n0, NN, tid);
}

// ---------------------------------------------------------------------------
// combine1: by<8: h = sigmoid(sum w1*z1 + b1) -> A2 + z2t k=0
//           by>=8: side work (w2 fp32->bf16)
// ---------------------------------------------------------------------------
__global__ __launch_bounds__(256) void combine1_k(const float* __restrict__ x,
                                                  const unsigned short* __restrict__ xSbf,
                                                  const float* __restrict__ w1,
                                                  const float* __restrict__ b1,
                                                  const float* __restrict__ w2,
                                                  unsigned short* __restrict__ A2,
                                                  unsigned short* __restrict__ z2t,
                                                  unsigned short* __restrict__ w2bf) {
    const int tid = threadIdx.x;
    if (blockIdx.y >= 8) {
        // side: w2 cvt (229376 float4s)
        const int sb = (blockIdx.y - 8) * 16 + blockIdx.x;  // 0..127
        for (long i4 = (long)sb * 256 + tid; i4 < 229376L; i4 += 32768L) {
            const float4 v = *(const float4*)&w2[i4 * 4];
            u16x4 pk;
            pk[0] = f2bf(v.x); pk[1] = f2bf(v.y);
            pk[2] = f2bf(v.z); pk[3] = f2bf(v.w);
            *(u16x4*)&w2bf[i4 * 4] = pk;
        }
        return;
    }
    __shared__ float w1s[NF1 * NK1 * NG1];
    for (int i = tid; i < NF1 * NK1 * NG1; i += 256) w1s[i] = w1[i];
    __syncthreads();

    const int b = blockIdx.y;
    const int n = blockIdx.x * 128 + (tid & 127);
    const int fh = tid >> 7;

    float accv[32];
#pragma unroll
    for (int f = 0; f < 32; ++f) accv[f] = 0.f;

    for (int k = 0; k < NK1; ++k) {
        float vv[NG1];
#pragma unroll
        for (int g = 0; g < NG1; ++g) {
            if (k == 0) vv[g] = x[(long)(b * 8 + g) * NN + n];
            else vv[g] = bf2f(xSbf[(long)(k - 1) * XSL + (long)(b * 8 + g) * NN + n]);
        }
#pragma unroll
        for (int f = 0; f < 32; ++f) {
            const float* wp = &w1s[((fh * 32 + f) * NK1 + k) * NG1];
            float s = 0.f;
#pragma unroll
            for (int g = 0; g < NG1; ++g) s += vv[g] * wp[g];
            accv[f] += s;
        }
    }
    unsigned short hb[32];
#pragma unroll
    for (int f = 0; f < 32; ++f) {
        const int fg = fh * 32 + f;
        const float h = sigmoidf_(accv[f] + b1[fg]);
        hb[f] = f2bf(h);
        A2[(long)(b * 64 + fg) * NN + n] = hb[f];
    }
    const long zb = ((long)(b * NN + n)) * KG2 + fh * 32;
#pragma unroll
    for (int c = 0; c < 4; ++c) {
        short8 v;
#pragma unroll
        for (int jj = 0; jj < 8; ++jj) v[jj] = (short)hb[c * 8 + jj];
        *(short8*)&z2t[zb + c * 8] = v;
    }
}

// ---------------------------------------------------------------------------
// g3_k: partial[np][m][2] = wlin . sigmoid(w2 @ z2 + b2), atomic-free.
// R11-proven form: BM=128, BN=256, 512 thr, BK=64 single-buffer m97,
// XOR-swizzled LDS both sides, batch-aligned XCD swizzle, (512,4) bounds.
// ---------------------------------------------------------------------------
__global__ __launch_bounds__(512, 4) void g3_k(
    const unsigned short* __restrict__ w2bf,
    const unsigned short* __restrict__ z2t,
    const float* __restrict__ b2, const float* __restrict__ wlin,
    float* __restrict__ partial) {
    __shared__ __attribute__((aligned(16))) unsigned short Asm[128 * 64];  // 16 KB
    __shared__ __attribute__((aligned(16))) unsigned short Bsm[256 * 64];  // 32 KB
    __shared__ float ored[128][2];                                         //  1 KB
    const int tid = threadIdx.x;
    const int bid = blockIdx.x;                     // 1024 blocks
    const int xcd = bid & 7, j = bid >> 3;          // j in [0,128)
    const int np = xcd * 8 + (j >> 4);              // n-panel id [0,64)
    const int n0 = np * 256;                        // batch = np>>3 = xcd
    const int m0 = (j & 15) * 128;                  // 16 m-tiles
    const int lane = tid & 63, wv = tid >> 6;       // 8 waves
    const int q = lane >> 4, r = lane & 15;
    const int wm = (wv >> 2) * 64, wn = (wv & 3) * 64;  // 2m x 4n wave grid
    const int qs = (tid & 7) ^ ((tid >> 3) & 7);    // pre-swizzled source quad
    const int rx = r & 7;                           // row&7 for frag reads

    const unsigned short* Ap = w2bf + (long)m0 * KG2;
    const unsigned short* Bp = z2t + (long)n0 * KG2;

    f32x4 acc[4][4];
#pragma unroll
    for (int i = 0; i < 4; ++i)
#pragma unroll
        for (int j2 = 0; j2 < 4; ++j2) acc[i][j2] = (f32x4){0.f, 0.f, 0.f, 0.f};

    for (int t = 0; t < 7; ++t) {   // K = 448 = 7 x 64
        const int k0 = t * 64;
#pragma unroll
        for (int c = 0; c < 2; ++c) {   // A: 128 rows x 64, 2 passes
            const int row = (tid >> 3) + c * 64;
            const unsigned short* gp = Ap + (long)row * KG2 + k0 + qs * 8;
            char* lb = (char*)Asm + c * 8192 + wv * 1024;  // wave-uniform base
            __builtin_amdgcn_global_load_lds(
                (const __attribute__((address_space(1))) void*)gp,
                (__attribute__((address_space(3))) void*)lb, 16, 0, 0);
        }
#pragma unroll
        for (int c = 0; c < 4; ++c) {   // B: 256 rows x 64, 4 passes
            const int row = (tid >> 3) + c * 64;
            const unsigned short* gp = Bp + (long)row * KG2 + k0 + qs * 8;
            char* lb = (char*)Bsm + c * 8192 + wv * 1024;
            __builtin_amdgcn_global_load_lds(
                (const __attribute__((address_space(1))) void*)gp,
                (__attribute__((address_space(3))) void*)lb, 16, 0, 0);
        }
        __syncthreads();
#pragma unroll
        for (int kk = 0; kk < 2; ++kk) {
            short8 af[4], bfv[4];
#pragma unroll
            for (int i = 0; i < 4; ++i)
                af[i] = *(const short8*)&Asm[(wm + i * 16 + r) * 64 +
                                             (((kk * 4 + q) ^ rx) * 8)];
#pragma unroll
            for (int j2 = 0; j2 < 4; ++j2)
                bfv[j2] = *(const short8*)&Bsm[(wn + j2 * 16 + r) * 64 +
                                               (((kk * 4 + q) ^ rx) * 8)];
#pragma unroll
            for (int i = 0; i < 4; ++i)
#pragma unroll
                for (int j2 = 0; j2 < 4; ++j2)
                    acc[i][j2] = __builtin_amdgcn_mfma_f32_16x16x32_bf16(
                        af[i], bfv[j2], acc[i][j2], 0, 0, 0);
        }
        __syncthreads();
    }

    // fused epilogue: sigmoid + dot(wlin) + LDS reduce -> private partial tile
    if (tid < 128) { ored[tid][0] = 0.f; ored[tid][1] = 0.f; }
    __syncthreads();
    float wl0[4], wl1[4];
#pragma unroll
    for (int j2 = 0; j2 < 4; ++j2) {
        const int nn = (n0 + wn + j2 * 16 + r) & (NN - 1);
        wl0[j2] = wlin[nn];
        wl1[j2] = wlin[NN + nn];
    }
#pragma unroll
    for (int i = 0; i < 4; ++i) {
#pragma unroll
        for (int e = 0; e < 4; ++e) {
            const int lrow = wm + i * 16 + q * 4 + e;
            const float bs = b2[m0 + lrow];
            float p0 = 0.f, p1 = 0.f;
#pragma unroll
            for (int j2 = 0; j2 < 4; ++j2) {
                const float s = sigmoidf_(acc[i][j2][e] + bs);
                p0 += s * wl0[j2];
                p1 += s * wl1[j2];
            }
#pragma unroll
            for (int mk = 1; mk < 16; mk <<= 1) {
                p0 += __shfl_xor(p0, mk);
                p1 += __shfl_xor(p1, mk);
            }
            if (r == 0) {
                atomicAdd(&ored[lrow][0], p0);   // LDS atomic (intra-block)
                atomicAdd(&ored[lrow][1], p1);
            }
        }
    }
    __syncthreads();
    // non-atomic private store: partial[(np*2048 + m0+i)*2 + o]
    float* pp = partial + ((long)np * NN + m0) * 2;
    if (tid < 128) {
        pp[tid * 2 + 0] = ored[tid][0];
        pp[tid * 2 + 1] = ored[tid][1];
    }
}

// ---------------------------------------------------------------------------
// finish: out[b*4096 + f*2 + o] = |sigmoid(sum_{s<8} partial[((b*8+s)*2048+f)*2+o]
//                                          + blin[o])|
// ---------------------------------------------------------------------------
__global__ __launch_bounds__(256) void finish_k(const float* __restrict__ partial,
                                                const float* __restrict__ blin,
                                                float* __restrict__ out) {
    const int i = blockIdx.x * 256 + threadIdx.x;   // 32768 outputs
    if (i >= 32768) return;
    const int b = i >> 12;
    const int fo = i & 4095;                        // f*2 + o
    float s = 0.f;
#pragma unroll
    for (int p = 0; p < 8; ++p)
        s += partial[(long)(b * 8 + p) * 4096 + fo];
    out[i] = fabsf(sigmoidf_(s + blin[i & 1]));
}

// ---------------------------------------------------------------------------
extern "C" void kernel_launch(void* const* d_in, const int* in_sizes, int n_in,
                              void* d_out, int out_size, void* d_ws, size_t ws_size,
                              hipStream_t stream) {
    const float* x      = (const float*)d_in[0];
    const float* terms1 = (const float*)d_in[1];  // slices 0,1 are S0,S1
    const float* w1     = (const float*)d_in[3];
    const float* b1     = (const float*)d_in[4];
    const float* w2     = (const float*)d_in[5];
    const float* b2     = (const float*)d_in[6];
    const float* wlin   = (const float*)d_in[7];
    const float* blin   = (const float*)d_in[8];
    float* out = (float*)d_out;

    char* ws = (char*)d_ws;
    unsigned short* xbf   = (unsigned short*)(ws + 0);          //   262144 B
    unsigned short* w2bf  = (unsigned short*)(ws + 262144);     //  1835008 B
    unsigned short* St    = (unsigned short*)(ws + 2097152);    // 16777216 B
    unsigned short* xSbf  = (unsigned short*)(ws + 18874368);   //  3670016 B
    unsigned short* A2    = (unsigned short*)(ws + 22544384);   //  2097152 B
    unsigned short* hS1bf = (unsigned short*)(ws + 24641536);   //  4194304 B
    unsigned short* z2t   = (unsigned short*)(ws + 28835840);   // 14680064 B
    float*          part  = (float*)(ws + 43515904);            //  1048576 B

    // 1) prep: St transpose + x cvt
    prep_k<<<dim3(64, 64, 3), 256, 0, stream>>>(terms1, x, St, xbf);

    // 2) G1 chain (M=64, N=2048, K=2048), BK=64 swizzled, PIPE=6
    g1_k<6><<<dim3(32, 1, 2), 256, 0, stream>>>(xbf, 0L, 30, St, xSbf);
    g1_k<6><<<dim3(32, 1, 4), 256, 0, stream>>>(xSbf, XSL, 1, St, xSbf + 2 * XSL);
    g1_k<6><<<dim3(32, 1, 8), 256, 0, stream>>>(xSbf + 2 * XSL, XSL, 1, St,
                                                xSbf + 6 * XSL);

    // 3) combine1 -> A2 + z2t k=0; side blocks do w2 cvt
    combine1_k<<<dim3(16, 16), 256, 0, stream>>>(x, xSbf, w1, b1, w2, A2, z2t,
                                                 w2bf);

    // 4) G2 chain (BN=128, BK=64 swizzled, PIPE=3): hS1 then hS2
    g2_k<3, true><<<dim3(16, 8, 2), 256, 0, stream>>>(A2, 0L, 30, St, z2t, 1,
                                                      hS1bf);
    g2_k<3, false><<<dim3(16, 8, 4), 256, 0, stream>>>(hS1bf, HSL, 1, St, z2t, 3,
                                                       nullptr);

    // 5) G3 (R11 single-buffer, atomic-free) + 6) finish reduce
    g3_k<<<1024, 512, 0, stream>>>(w2bf, z2t, b2, wlin, part);
    finish_k<<<128, 256, 0, stream>>>(part, blin, out);
}

// Round 15
// 170.798 us; speedup vs baseline: 1.1738x; 1.0034x over previous
//
#include <hip/hip_runtime.h>

typedef __attribute__((ext_vector_type(8))) short short8;
typedef __attribute__((ext_vector_type(4))) float f32x4;
typedef __attribute__((ext_vector_type(4))) unsigned short u16x4;

#define NN 2048
#define KG2 448
#define NK1 15
#define NG1 8
#define NF1 64
#define SLICE (2048L * 2048L)
#define XSL (64L * 2048L)
#define HSL (512L * 2048L)

static __device__ __forceinline__ unsigned short f2bf(float v) {
    union { float f; unsigned int u; } a; a.f = v;
    unsigned int u = a.u;
    u += 0x7fffu + ((u >> 16) & 1u);   // round-to-nearest-even
    return (unsigned short)(u >> 16);
}
static __device__ __forceinline__ float bf2f(unsigned short s) {
    union { float f; unsigned int u; } a; a.u = ((unsigned int)s) << 16;
    return a.f;
}
static __device__ __forceinline__ float sigmoidf_(float v) {
    return 1.f / (1.f + __expf(-v));
}
template <int N> static __device__ __forceinline__ void waitvm() {
    asm volatile("s_waitcnt vmcnt(%0)" ::"n"(N) : "memory");
}
template <int LPT> static __device__ __forceinline__ void waitrem(int rem) {
    if (rem >= 7) waitvm<7 * LPT>();
    else if (rem == 6) waitvm<6 * LPT>();
    else if (rem == 5) waitvm<5 * LPT>();
    else if (rem == 4) waitvm<4 * LPT>();
    else if (rem == 3) waitvm<3 * LPT>();
    else if (rem == 2) waitvm<2 * LPT>();
    else if (rem == 1) waitvm<1 * LPT>();
    else waitvm<0>();
}

// ---------------------------------------------------------------------------
// gemm_core64 (256 threads): C[BM,BN] += A[BM,K] @ Bt[BN,K]^T, bf16, BK=64.
// XOR-swizzled LDS on BOTH sides (rule #21): thread loads global quad
// qs=(tid&7)^(row&7) into linear LDS slot tid&7; frag read XORs back.
// 2-way bank conflicts (free, m136). Counted-vmcnt PIPE-deep prefetch;
// PIPE=1 degenerates to the m97 2-barrier single-buffer loop.
// ---------------------------------------------------------------------------
template <int BM, int BN, int PIPE>
static __device__ __forceinline__ void gemm_core64(
    const unsigned short* __restrict__ Ap, int lda,
    const unsigned short* __restrict__ Bp, int ldb, int K,
    unsigned short* Alds, unsigned short* Blds,
    f32x4 (&acc)[BM / 32][BN / 32], int tid) {
    constexpr int MI = BM / 32, NI = BN / 32;
    constexpr int APASS = BM / 32, BPASS = BN / 32;   // 32 rows per pass
    constexpr int LPT = APASS + BPASS;
    const int lane = tid & 63;
    const int wv = tid >> 6;
    const int q = lane >> 4, r = lane & 15;
    const int wm = (wv >> 1) * (BM / 2), wn = (wv & 1) * (BN / 2);
    const int qs = (tid & 7) ^ ((tid >> 3) & 7);      // pre-swizzled quad
    const int rx = r & 7;

    auto stage = [&](int k0, int buf) {
        unsigned short* Ab = Alds + buf * (BM * 64);
        unsigned short* Bb = Blds + buf * (BN * 64);
#pragma unroll
        for (int c = 0; c < APASS; ++c) {
            const int row = (tid >> 3) + c * 32;
            const unsigned short* gp = Ap + (long)row * lda + k0 + qs * 8;
            char* lb = (char*)Ab + c * 4096 + wv * 1024;   // wave-uniform
            __builtin_amdgcn_global_load_lds(
                (const __attribute__((address_space(1))) void*)gp,
                (__attribute__((address_space(3))) void*)lb, 16, 0, 0);
        }
#pragma unroll
        for (int c = 0; c < BPASS; ++c) {
            const int row = (tid >> 3) + c * 32;
            const unsigned short* gp = Bp + (long)row * ldb + k0 + qs * 8;
            char* lb = (char*)Bb + c * 4096 + wv * 1024;
            __builtin_amdgcn_global_load_lds(
                (const __attribute__((address_space(1))) void*)gp,
                (__attribute__((address_space(3))) void*)lb, 16, 0, 0);
        }
    };
    auto compute = [&](int buf) {
        const unsigned short* Ab = Alds + buf * (BM * 64);
        const unsigned short* Bb = Blds + buf * (BN * 64);
#pragma unroll
        for (int kk = 0; kk < 2; ++kk) {
            short8 af[MI], bfv[NI];
#pragma unroll
            for (int i = 0; i < MI; ++i)
                af[i] = *(const short8*)&Ab[(wm + i * 16 + r) * 64 +
                                            (((kk * 4 + q) ^ rx) * 8)];
#pragma unroll
            for (int j = 0; j < NI; ++j)
                bfv[j] = *(const short8*)&Bb[(wn + j * 16 + r) * 64 +
                                             (((kk * 4 + q) ^ rx) * 8)];
#pragma unroll
            for (int i = 0; i < MI; ++i)
#pragma unroll
                for (int j = 0; j < NI; ++j)
                    acc[i][j] = __builtin_amdgcn_mfma_f32_16x16x32_bf16(
                        af[i], bfv[j], acc[i][j], 0, 0, 0);
        }
    };

    const int NT = K >> 6;   // BK = 64
#pragma unroll
    for (int p = 0; p < PIPE - 1; ++p)
        if (p < NT) stage(p * 64, p);
    for (int t = 0; t < NT; ++t) {
        if (t + PIPE - 1 < NT)
            stage((t + PIPE - 1) * 64, (t + PIPE - 1) % PIPE);
        int rem = NT - 1 - t;
        if (rem > PIPE - 1) rem = PIPE - 1;
        waitrem<LPT>(rem);
        __builtin_amdgcn_s_barrier();
        compute(t % PIPE);
        __builtin_amdgcn_s_barrier();
    }
}

// epilogue: plain bf16 row-major store. C/D layout: col=lane&15, row=q*4+e
template <int BM, int BN>
static __device__ __forceinline__ void epi_bf16(
    f32x4 (&acc)[BM / 32][BN / 32], unsigned short* dst, int ld, int tid) {
    const int lane = tid & 63, wv = tid >> 6, q = lane >> 4, r = lane & 15;
    const int wm = (wv >> 1) * (BM / 2), wn = (wv & 1) * (BN / 2);
#pragma unroll
    for (int i = 0; i < BM / 32; ++i)
#pragma unroll
        for (int j = 0; j < BN / 32; ++j)
#pragma unroll
            for (int e = 0; e < 4; ++e)
                dst[(long)(wm + i * 16 + q * 4 + e) * ld + wn + j * 16 + r] =
                    f2bf(acc[i][j][e]);
}

// epilogue: z2t scatter. rows = b*64+g -> z2t[(b*2048+col)*448 + kidx*64 + g]
template <int BM, int BN>
static __device__ __forceinline__ void epi_z2t(
    f32x4 (&acc)[BM / 32][BN / 32], unsigned short* z2t,
    int m0, int n0, int kidx, int tid) {
    const int lane = tid & 63, wv = tid >> 6, q = lane >> 4, r = lane & 15;
    const int wm = (wv >> 1) * (BM / 2), wn = (wv & 1) * (BN / 2);
#pragma unroll
    for (int i = 0; i < BM / 32; ++i)
#pragma unroll
        for (int j = 0; j < BN / 32; ++j) {
            const int row0 = m0 + wm + i * 16 + q * 4;
            const int bb = row0 >> 6, gg = row0 & 63;
            const int col = n0 + wn + j * 16 + r;
            u16x4 pk;
            pk[0] = f2bf(acc[i][j][0]); pk[1] = f2bf(acc[i][j][1]);
            pk[2] = f2bf(acc[i][j][2]); pk[3] = f2bf(acc[i][j][3]);
            *(u16x4*)&z2t[((long)bb * NN + col) * KG2 + kidx * 64 + gg] = pk;
        }
}

// ---------------------------------------------------------------------------
// prep: St transpose+cvt (z<2); x cvt (z==2)
// ---------------------------------------------------------------------------
__global__ __launch_bounds__(256) void prep_k(const float* __restrict__ S,
                                              const float* __restrict__ x,
                                              unsigned short* __restrict__ St,
                                              unsigned short* __restrict__ xbf) {
    if (blockIdx.z < 2) {
        __shared__ float t[32][33];
        const int e = blockIdx.z;
        const int n0 = blockIdx.x * 32, k0 = blockIdx.y * 32;
        const int tx = threadIdx.x & 31, ty = threadIdx.x >> 5;
        const float* src = S + (long)e * SLICE;
        unsigned short* dst = St + (long)e * SLICE;
#pragma unroll
        for (int i = 0; i < 4; ++i)
            t[ty + i * 8][tx] = src[(long)(k0 + ty + i * 8) * NN + n0 + tx];
        __syncthreads();
#pragma unroll
        for (int i = 0; i < 4; ++i)
            dst[(long)(n0 + ty + i * 8) * NN + k0 + tx] = f2bf(t[tx][ty + i * 8]);
    } else {
        const long i = (long)(blockIdx.y * 64 + blockIdx.x) * 256 + threadIdx.x;
        if (i < 131072L) xbf[i] = f2bf(x[i]);
    }
}

// ---------------------------------------------------------------------------
// g1_k: out[z] = A_slice @ St[z&1]^T   (M=64, K=2048), BK=64, BN templated
// ---------------------------------------------------------------------------
template <int PIPE, int BN>
__global__ __launch_bounds__(256) void g1_k(const unsigned short* __restrict__ A,
                                            long a_bstride, int a_shr,
                                            const unsigned short* __restrict__ St,
                                            unsigned short* __restrict__ outp) {
    __shared__ __attribute__((aligned(16))) unsigned short smem[PIPE * (64 + BN) * 64];
    const int tid = threadIdx.x;
    const int n0 = blockIdx.x * BN;
    const int z = blockIdx.z;
    const unsigned short* Ap = A + (long)(z >> a_shr) * a_bstride;
    const unsigned short* Bp = St + (long)(z & 1) * SLICE + (long)n0 * NN;

    f32x4 acc[2][BN / 32];
#pragma unroll
    for (int i = 0; i < 2; ++i)
#pragma unroll
        for (int j = 0; j < BN / 32; ++j) acc[i][j] = (f32x4){0.f, 0.f, 0.f, 0.f};
    gemm_core64<64, BN, PIPE>(Ap, NN, Bp, NN, NN, smem, smem + PIPE * 64 * 64,
                              acc, tid);
    epi_bf16<64, BN>(acc, outp + (long)z * XSL + n0, NN, tid);
}

// ---------------------------------------------------------------------------
// g2_k: slice GEMM (M=512 via by, BN=128, K=2048) -> z2t scatter (+opt chain)
// BK=64, PIPE=3 (72 KB LDS -> 2 blocks/CU)
// ---------------------------------------------------------------------------
template <int PIPE, bool CHAIN>
__global__ __launch_bounds__(256) void g2_k(const unsigned short* __restrict__ A,
                                            long a_bstride, int a_shr,
                                            const unsigned short* __restrict__ St,
                                            unsigned short* __restrict__ z2t,
                                            int kbase,
                                            unsigned short* __restrict__ chain) {
    __shared__ __attribute__((aligned(16))) unsigned short smem[PIPE * 192 * 64];
    const int tid = threadIdx.x;
    const int n0 = blockIdx.x * 128;
    const int m0 = blockIdx.y * 64;
    const int z = blockIdx.z;
    const unsigned short* Ap = A + (long)(z >> a_shr) * a_bstride + (long)m0 * NN;
    const unsigned short* Bp = St + (long)(z & 1) * SLICE + (long)n0 * NN;

    f32x4 acc[2][4];
#pragma unroll
    for (int i = 0; i < 2; ++i)
#pragma unroll
        for (int j = 0; j < 4; ++j) acc[i][j] = (f32x4){0.f, 0.f, 0.f, 0.f};
    gemm_core64<64, 128, PIPE>(Ap, NN, Bp, NN, NN, smem, smem + PIPE * 64 * 64,
                               acc, tid);
    epi_z2t<64, 128>(acc, z2t, m0, n0, kbase + z, tid);
    if (CHAIN)
        epi_bf16<64, 128>(acc, chain + (long)z * HSL + (long)m0 * NN + n0, NN, tid);
}

// ---------------------------------------------------------------------------
// combine1: by<8: h = sigmoid(sum w1*z1 + b1) -> A2 + z2t k=0
//           by>=8: side work (w2 fp32->bf16)
// ---------------------------------------------------------------------------
__global__ __launch_bounds__(256) void combine1_k(const float* __restrict__ x,
                                                  const unsigned short* __restrict__ xSbf,
                                                  const float* __restrict__ w1,
                                                  const float* __restrict__ b1,
                                                  const float* __restrict__ w2,
                                                  unsigned short* __restrict__ A2,
                                                  unsigned short* __restrict__ z2t,
                                                  unsigned short* __restrict__ w2bf) {
    const int tid = threadIdx.x;
    if (blockIdx.y >= 8) {
        // side: w2 cvt (229376 float4s)
        const int sb = (blockIdx.y - 8) * 16 + blockIdx.x;  // 0..127
        for (long i4 = (long)sb * 256 + tid; i4 < 229376L; i4 += 32768L) {
            const float4 v = *(const float4*)&w2[i4 * 4];
            u16x4 pk;
            pk[0] = f2bf(v.x); pk[1] = f2bf(v.y);
            pk[2] = f2bf(v.z); pk[3] = f2bf(v.w);
            *(u16x4*)&w2bf[i4 * 4] = pk;
        }
        return;
    }
    __shared__ float w1s[NF1 * NK1 * NG1];
    for (int i = tid; i < NF1 * NK1 * NG1; i += 256) w1s[i] = w1[i];
    __syncthreads();

    const int b = blockIdx.y;
    const int n = blockIdx.x * 128 + (tid & 127);
    const int fh = tid >> 7;

    float accv[32];
#pragma unroll
    for (int f = 0; f < 32; ++f) accv[f] = 0.f;

    for (int k = 0; k < NK1; ++k) {
        float vv[NG1];
#pragma unroll
        for (int g = 0; g < NG1; ++g) {
            if (k == 0) vv[g] = x[(long)(b * 8 + g) * NN + n];
            else vv[g] = bf2f(xSbf[(long)(k - 1) * XSL + (long)(b * 8 + g) * NN + n]);
        }
#pragma unroll
        for (int f = 0; f < 32; ++f) {
            const float* wp = &w1s[((fh * 32 + f) * NK1 + k) * NG1];
            float s = 0.f;
#pragma unroll
            for (int g = 0; g < NG1; ++g) s += vv[g] * wp[g];
            accv[f] += s;
        }
    }
    unsigned short hb[32];
#pragma unroll
    for (int f = 0; f < 32; ++f) {
        const int fg = fh * 32 + f;
        const float h = sigmoidf_(accv[f] + b1[fg]);
        hb[f] = f2bf(h);
        A2[(long)(b * 64 + fg) * NN + n] = hb[f];
    }
    const long zb = ((long)(b * NN + n)) * KG2 + fh * 32;
#pragma unroll
    for (int c = 0; c < 4; ++c) {
        short8 v;
#pragma unroll
        for (int jj = 0; jj < 8; ++jj) v[jj] = (short)hb[c * 8 + jj];
        *(short8*)&z2t[zb + c * 8] = v;
    }
}

// ---------------------------------------------------------------------------
// g3_k: partial[np][m][2] = wlin . sigmoid(w2 @ z2 + b2), atomic-free.
// 128x128 tile (m103: optimal for the 2-barrier structure), 256 thr,
// BK=64 single-buffer swizzled via gemm_core64<128,128,1>. LDS 33 KB,
// (256,4) bounds -> 4 blocks/CU TLP. Batch-aligned XCD swizzle: XCD k owns
// n in [k*2048,(k+1)*2048) -> z2t slice (1.75 MB) + w2 (1.8 MB) L2-resident.
// ---------------------------------------------------------------------------
__global__ __launch_bounds__(256, 4) void g3_k(
    const unsigned short* __restrict__ w2bf,
    const unsigned short* __restrict__ z2t,
    const float* __restrict__ b2, const float* __restrict__ wlin,
    float* __restrict__ partial) {
    __shared__ __attribute__((aligned(16))) unsigned short smem[256 * 64];  // 32 KB
    __shared__ float ored[128][2];                                          //  1 KB
    const int tid = threadIdx.x;
    const int bid = blockIdx.x;                     // 2048 blocks
    const int xcd = bid & 7, j = bid >> 3;          // j in [0,256)
    const int np = xcd * 16 + (j >> 4);             // n-panel id [0,128)
    const int n0 = np * 128;                        // batch = np>>4 = xcd
    const int m0 = (j & 15) * 128;                  // 16 m-tiles
    const int lane = tid & 63, wv = tid >> 6;       // 4 waves, 2m x 2n
    const int q = lane >> 4, r = lane & 15;
    const int wm = (wv >> 1) * 64, wn = (wv & 1) * 64;

    const unsigned short* Ap = w2bf + (long)m0 * KG2;
    const unsigned short* Bp = z2t + (long)n0 * KG2;

    f32x4 acc[4][4];
#pragma unroll
    for (int i = 0; i < 4; ++i)
#pragma unroll
        for (int j2 = 0; j2 < 4; ++j2) acc[i][j2] = (f32x4){0.f, 0.f, 0.f, 0.f};

    gemm_core64<128, 128, 1>(Ap, KG2, Bp, KG2, KG2,
                             smem, smem + 128 * 64, acc, tid);

    // fused epilogue: sigmoid + dot(wlin) + LDS reduce -> private partial tile
    if (tid < 128) { ored[tid][0] = 0.f; ored[tid][1] = 0.f; }
    __syncthreads();
    float wl0[4], wl1[4];
#pragma unroll
    for (int j2 = 0; j2 < 4; ++j2) {
        const int nn = (n0 + wn + j2 * 16 + r) & (NN - 1);
        wl0[j2] = wlin[nn];
        wl1[j2] = wlin[NN + nn];
    }
#pragma unroll
    for (int i = 0; i < 4; ++i) {
#pragma unroll
        for (int e = 0; e < 4; ++e) {
            const int lrow = wm + i * 16 + q * 4 + e;
            const float bs = b2[m0 + lrow];
            float p0 = 0.f, p1 = 0.f;
#pragma unroll
            for (int j2 = 0; j2 < 4; ++j2) {
                const float s = sigmoidf_(acc[i][j2][e] + bs);
                p0 += s * wl0[j2];
                p1 += s * wl1[j2];
            }
#pragma unroll
            for (int mk = 1; mk < 16; mk <<= 1) {
                p0 += __shfl_xor(p0, mk);
                p1 += __shfl_xor(p1, mk);
            }
            if (r == 0) {
                atomicAdd(&ored[lrow][0], p0);   // LDS atomic (intra-block)
                atomicAdd(&ored[lrow][1], p1);
            }
        }
    }
    __syncthreads();
    // non-atomic private store: partial[(np*2048 + m0+i)*2 + o]
    float* pp = partial + ((long)np * NN + m0) * 2;
    if (tid < 128) {
        pp[tid * 2 + 0] = ored[tid][0];
        pp[tid * 2 + 1] = ored[tid][1];
    }
}

// ---------------------------------------------------------------------------
// finish: out[b*4096+f*2+o] = |sigmoid(sum_{p<16} partial[(b*16+p)*4096+f*2+o]
//                                      + blin[o])|
// ---------------------------------------------------------------------------
__global__ __launch_bounds__(256) void finish_k(const float* __restrict__ partial,
                                                const float* __restrict__ blin,
                                                float* __restrict__ out) {
    const int i = blockIdx.x * 256 + threadIdx.x;   // 32768 outputs
    if (i >= 32768) return;
    const int b = i >> 12;
    const int fo = i & 4095;                        // f*2 + o
    float s = 0.f;
#pragma unroll
    for (int p = 0; p < 16; ++p)
        s += partial[(long)(b * 16 + p) * 4096 + fo];
    out[i] = fabsf(sigmoidf_(s + blin[i & 1]));
}

// ---------------------------------------------------------------------------
extern "C" void kernel_launch(void* const* d_in, const int* in_sizes, int n_in,
                              void* d_out, int out_size, void* d_ws, size_t ws_size,
                              hipStream_t stream) {
    const float* x      = (const float*)d_in[0];
    const float* terms1 = (const float*)d_in[1];  // slices 0,1 are S0,S1
    const float* w1     = (const float*)d_in[3];
    const float* b1     = (const float*)d_in[4];
    const float* w2     = (const float*)d_in[5];
    const float* b2     = (const float*)d_in[6];
    const float* wlin   = (const float*)d_in[7];
    const float* blin   = (const float*)d_in[8];
    float* out = (float*)d_out;

    char* ws = (char*)d_ws;
    unsigned short* xbf   = (unsigned short*)(ws + 0);          //   262144 B
    unsigned short* w2bf  = (unsigned short*)(ws + 262144);     //  1835008 B
    unsigned short* St    = (unsigned short*)(ws + 2097152);    // 16777216 B
    unsigned short* xSbf  = (unsigned short*)(ws + 18874368);   //  3670016 B
    unsigned short* A2    = (unsigned short*)(ws + 22544384);   //  2097152 B
    unsigned short* hS1bf = (unsigned short*)(ws + 24641536);   //  4194304 B
    unsigned short* z2t   = (unsigned short*)(ws + 28835840);   // 14680064 B
    float*          part  = (float*)(ws + 43515904);            //  2097152 B

    // 1) prep: St transpose + x cvt
    prep_k<<<dim3(64, 64, 3), 256, 0, stream>>>(terms1, x, St, xbf);

    // 2) G1 chain (M=64, K=2048), BK=64 swizzled, PIPE=6
    //    L1/L2 use BN=32 (2x blocks for the worst-occupancy launches)
    g1_k<6, 32><<<dim3(64, 1, 2), 256, 0, stream>>>(xbf, 0L, 30, St, xSbf);
    g1_k<6, 32><<<dim3(64, 1, 4), 256, 0, stream>>>(xSbf, XSL, 1, St,
                                                    xSbf + 2 * XSL);
    g1_k<6, 64><<<dim3(32, 1, 8), 256, 0, stream>>>(xSbf + 2 * XSL, XSL, 1, St,
                                                    xSbf + 6 * XSL);

    // 3) combine1 -> A2 + z2t k=0; side blocks do w2 cvt
    combine1_k<<<dim3(16, 16), 256, 0, stream>>>(x, xSbf, w1, b1, w2, A2, z2t,
                                                 w2bf);

    // 4) G2 chain (BN=128, BK=64 swizzled, PIPE=3): hS1 then hS2
    g2_k<3, true><<<dim3(16, 8, 2), 256, 0, stream>>>(A2, 0L, 30, St, z2t, 1,
                                                      hS1bf);
    g2_k<3, false><<<dim3(16, 8, 4), 256, 0, stream>>>(hS1bf, HSL, 1, St, z2t, 3,
                                                       nullptr);

    // 5) G3 (128x128, 4 blk/CU, atomic-free) + 6) finish reduce
    g3_k<<<2048, 256, 0, stream>>>(w2bf, z2t, b2, wlin, part);
    finish_k<<<128, 256, 0, stream>>>(part, blin, out);
}